// Round 3
// baseline (1104.541 us; speedup 1.0000x reference)
//
#include <hip/hip_runtime.h>
#include <math.h>

#define NSC 64
#define NVC 64
#define EMB 32
#define NTYPES 20
#define NB 8
#define RH 16
#define LAYERS 2
#define CUTV 3.5f
#define HSTEP 0.1f

// ---------------------------------------------------------------------------
// Exact LAPACK-style Householder QR of Ku^T (64x2) -> Q (64x2), matching
// jnp/np.linalg.qr sign conventions (sgeqr2 + sorg2r).
// ---------------------------------------------------------------------------
__global__ void qr_kernel(const float* __restrict__ Ku, float* __restrict__ Q)
{
  if (threadIdx.x != 0 || blockIdx.x != 0) return;
  float A0[64], A1[64], v0[64], v1[64], t1[64];
  for (int i = 0; i < 64; ++i) { A0[i] = Ku[i]; A1[i] = Ku[64 + i]; }
  float alpha = A0[0];
  float xn2 = 0.f;
  for (int i = 1; i < 64; ++i) xn2 += A0[i] * A0[i];
  float beta0 = -copysignf(sqrtf(alpha * alpha + xn2), alpha);
  float tau0 = (beta0 - alpha) / beta0;
  float inv0 = 1.f / (alpha - beta0);
  v0[0] = 1.f;
  for (int i = 1; i < 64; ++i) v0[i] = A0[i] * inv0;
  float w = 0.f;
  for (int i = 0; i < 64; ++i) w += v0[i] * A1[i];
  for (int i = 0; i < 64; ++i) A1[i] -= tau0 * w * v0[i];
  float alpha1 = A1[1];
  float xn2b = 0.f;
  for (int i = 2; i < 64; ++i) xn2b += A1[i] * A1[i];
  float beta1 = -copysignf(sqrtf(alpha1 * alpha1 + xn2b), alpha1);
  float tau1 = (beta1 - alpha1) / beta1;
  float inv1 = 1.f / (alpha1 - beta1);
  v1[0] = 0.f; v1[1] = 1.f;
  for (int i = 2; i < 64; ++i) v1[i] = A1[i] * inv1;
  for (int i = 0; i < 64; ++i) t1[i] = ((i == 1) ? 1.f : 0.f) - tau1 * v1[i];
  float d = 0.f;
  for (int i = 0; i < 64; ++i) d += v0[i] * t1[i];
  for (int i = 0; i < 64; ++i) {
    float q0 = ((i == 0) ? 1.f : 0.f) - tau0 * v0[i];
    float q1 = t1[i] - tau0 * d * v0[i];
    Q[i * 2 + 0] = q0;
    Q[i * 2 + 1] = q1;
  }
}

// ---------------------------------------------------------------------------
// State layout: st[node][p][lane], p in {0:s, 1:vx, 2:vy, 3:vz}; 256 floats/node.
// ---------------------------------------------------------------------------
__global__ void init_state(const float* __restrict__ x, const float* __restrict__ Qm,
                           float* __restrict__ st0, int* __restrict__ cnt, int n)
{
  const int i = blockIdx.x * 256 + threadIdx.x;
  const int node = i >> 6, lane = i & 63;
  if (node < n) {
    const float q0 = Qm[lane * 2 + 0], q1 = Qm[lane * 2 + 1];
    const float* xp = x + (size_t)node * 6;
    float* sp = st0 + (size_t)node * 256 + lane;
    sp[0]   = 0.f;
    sp[64]  = xp[0] * q0 + xp[3] * q1;
    sp[128] = xp[1] * q0 + xp[4] * q1;
    sp[192] = xp[2] * q0 + xp[5] * q1;
  }
  if (i < n) cnt[i] = 0;
}

__global__ void hist_kernel(const int* __restrict__ edst, int* __restrict__ cnt, int m)
{
  const int e = blockIdx.x * 256 + threadIdx.x;
  if (e < m) atomicAdd(&cnt[edst[e]], 1);
}

// Single-block exclusive scan of counts.
__global__ void scan_kernel(int* cnt, int* off, int n)
{
  __shared__ int lds[1024];
  const int t = threadIdx.x;
  const int CH = (n + 1023) >> 10;
  const int base = t * CH;
  int local[16];
  int run = 0;
  for (int j = 0; j < CH; ++j) {
    int v = (base + j < n) ? cnt[base + j] : 0;
    local[j] = run;
    run += v;
  }
  lds[t] = run;
  __syncthreads();
  for (int s = 1; s < 1024; s <<= 1) {
    int v = (t >= s) ? lds[t - s] : 0;
    __syncthreads();
    lds[t] += v;
    __syncthreads();
  }
  const int excl = lds[t] - run;
  for (int j = 0; j < CH; ++j) {
    if (base + j < n) {
      int o = excl + local[j];
      off[base + j] = o;
      cnt[base + j] = o;
    }
  }
  if (t == 1023) off[n] = lds[1023];
}

__global__ void scatter_kernel(const int* __restrict__ edst, int* __restrict__ cursor,
                               int* __restrict__ csr, int m)
{
  const int e = blockIdx.x * 256 + threadIdx.x;
  if (e < m) {
    int p = atomicAdd(&cursor[edst[e]], 1);
    csr[p] = e;
  }
}

// Edge arrays in CSR (destination-sorted) order — computed once.
__global__ void reorder_kernel(const int* __restrict__ csr,
                               const int* __restrict__ esrc, const int* __restrict__ edst,
                               int* __restrict__ esrc_s, int* __restrict__ edst_s, int m)
{
  const int k = blockIdx.x * 256 + threadIdx.x;
  if (k < m) {
    const int e = csr[k];
    esrc_s[k] = esrc[e];
    edst_s[k] = edst[e];
  }
}

// ---------------------------------------------------------------------------
// Per-(layer,type) folded self-connection weights, output-parallel.
// ---------------------------------------------------------------------------
__global__ void type_weights(const float* __restrict__ embed,
                             const float* __restrict__ Wss,
                             const float* __restrict__ Wsv,
                             float* __restrict__ Ws, float* __restrict__ Wv,
                             int total_s, int total_v)
{
  const int i = blockIdx.x * 256 + threadIdx.x;
  if (i < total_s) {
    const int bid = i >> 13;
    const int p = i & 8191;
    const int l = bid / NTYPES, t = bid % NTYPES;
    const int s = p >> 7, o = p & 127;
    const float* ar = embed + t * EMB;
    const float* wp = Wss + ((size_t)(l * 64 + s) * EMB) * 128 + o;
    float acc = 0.f;
    #pragma unroll
    for (int e = 0; e < EMB; ++e) acc = fmaf(ar[e], wp[e * 128], acc);
    Ws[i] = acc;
  } else {
    const int j = i - total_s;
    if (j < total_v) {
      const int bid = j >> 12;
      const int p = j & 4095;
      const int l = bid / NTYPES, t = bid % NTYPES;
      const int v = p >> 6, u = p & 63;
      const float* ar = embed + t * EMB;
      const float* wp = Wsv + ((size_t)(l * 64 + v) * EMB) * 64 + u;
      float acc = 0.f;
      #pragma unroll
      for (int e = 0; e < EMB; ++e) acc = fmaf(ar[e], wp[e * 64], acc);
      Wv[j] = acc;
    }
  }
}

// ---------------------------------------------------------------------------
// Per-edge geometry + first MLP layer, in CSR order.
// egeo[k] = [eaX,eaY,eaZ,pad, hid0..15]
// ---------------------------------------------------------------------------
__global__ void edge_geom(const float* __restrict__ xv,
                          const int* __restrict__ esrc_s, const int* __restrict__ edst_s,
                          const float* __restrict__ Wr1l, const float* __restrict__ br1l,
                          float* __restrict__ egeo, int m)
{
  const int k = blockIdx.x * 256 + threadIdx.x;
  if (k >= m) return;
  const int s = esrc_s[k], d = edst_s[k];
  const float ex = xv[(size_t)s * 6 + 0] - xv[(size_t)d * 6 + 0];
  const float ey = xv[(size_t)s * 6 + 1] - xv[(size_t)d * 6 + 1];
  const float ez = xv[(size_t)s * 6 + 2] - xv[(size_t)d * 6 + 2];
  const float len = sqrtf(ex * ex + ey * ey + ez * ez);
  const float invl = 1.f / len;
  const float u = len * (1.f / CUTV);
  const float vv = 2.f * (u - 1.f);
  float cut = 0.5f * (1.f - cosf((float)M_PI * vv));
  cut = (vv > 0.f) ? 0.f : cut;
  cut = (vv < -1.f) ? 1.f : cut;
  const float cc = cut * 1.7320508075688772f * invl;
  float4* outp = (float4*)(egeo + (size_t)k * 20);
  outp[0] = make_float4(cc * ex, cc * ey, cc * ez, 0.f);
  float bess[NB];
  const float amp = 2.1380899352993948f * invl;  // sqrt(2/CUT)*sqrt(NB)
  const float arg = (float)M_PI * len * (1.f / CUTV);
  #pragma unroll
  for (int kk = 0; kk < NB; ++kk) bess[kk] = amp * sinf(arg * (float)(kk + 1));
  float hid[RH];
  #pragma unroll
  for (int j = 0; j < RH; ++j) {
    float h = br1l[j];
    #pragma unroll
    for (int kk = 0; kk < NB; ++kk) h = fmaf(bess[kk], Wr1l[kk * RH + j], h);
    hid[j] = h / (1.f + expf(-h));   // silu
  }
  outp[1] = make_float4(hid[0], hid[1], hid[2], hid[3]);
  outp[2] = make_float4(hid[4], hid[5], hid[6], hid[7]);
  outp[3] = make_float4(hid[8], hid[9], hid[10], hid[11]);
  outp[4] = make_float4(hid[12], hid[13], hid[14], hid[15]);
}

// ---------------------------------------------------------------------------
// One wave per destination node; CSR-sequential edge streams; unroll-by-2.
// ---------------------------------------------------------------------------
#define DO_EDGE(G0,G1,G2,G3,G4,ss,vx,vy,vz)                                  \
  {                                                                          \
    const float hid[RH] = { G1.x,G1.y,G1.z,G1.w, G2.x,G2.y,G2.z,G2.w,        \
                            G3.x,G3.y,G3.z,G3.w, G4.x,G4.y,G4.z,G4.w };      \
    float wA = bA, wB = bB, wC = bC, wD = bD;                                \
    _Pragma("unroll")                                                        \
    for (int j = 0; j < RH; ++j) {                                           \
      wA = fmaf(hid[j], wr2A[j], wA);                                        \
      wB = fmaf(hid[j], wr2B[j], wB);                                        \
      wC = fmaf(hid[j], wr2C[j], wC);                                        \
      wD = fmaf(hid[j], wr2D[j], wD);                                        \
    }                                                                        \
    const float dt = vx * G0.x + vy * G0.y + vz * G0.z;                      \
    aS1 = fmaf(wB, dt, aS1);                                                 \
    aS2 = fmaf(wD, dt, aS2);                                                 \
    const float t = wA * ss;                                                 \
    aV0 += t * G0.x + wC * (vy * G0.z - vz * G0.y);                          \
    aV1 += t * G0.y + wC * (vz * G0.x - vx * G0.z);                          \
    aV2 += t * G0.z + wC * (vx * G0.y - vy * G0.x);                          \
  }

__global__ __launch_bounds__(256, 4) void gather_update(
    const int* __restrict__ off, const int* __restrict__ esrc_s,
    const float* __restrict__ egeo,
    const float* __restrict__ st_in, const int* __restrict__ nattr,
    const float* __restrict__ Ws, const float* __restrict__ Wv,
    const float* __restrict__ Wr2l, const float* __restrict__ br2l,
    const float* __restrict__ Qm,
    float* __restrict__ st_out, float* __restrict__ xv_out, int n)
{
  const int lane = threadIdx.x & 63;
  const int node = blockIdx.x * 4 + (threadIdx.x >> 6);
  if (node >= n) return;

  float wr2A[RH], wr2B[RH], wr2C[RH], wr2D[RH];
  #pragma unroll
  for (int j = 0; j < RH; ++j) {
    const float* r = Wr2l + j * 256 + lane;
    wr2A[j] = r[0]; wr2B[j] = r[64]; wr2C[j] = r[128]; wr2D[j] = r[192];
  }
  const float bA = br2l[lane], bB = br2l[64 + lane],
              bC = br2l[128 + lane], bD = br2l[192 + lane];

  float aS1 = 0.f, aS2 = 0.f, aV0 = 0.f, aV1 = 0.f, aV2 = 0.f;
  const int k0 = off[node], k1 = off[node + 1];
  int k = k0;
  for (; k + 2 <= k1; k += 2) {
    const int sA = esrc_s[k], sB = esrc_s[k + 1];
    const float4* gA = (const float4*)(egeo + (size_t)k * 20);
    const float4 A0 = gA[0], A1 = gA[1], A2 = gA[2], A3 = gA[3], A4 = gA[4];
    const float4 B0 = gA[5], B1 = gA[6], B2 = gA[7], B3 = gA[8], B4 = gA[9];
    const float* pA = st_in + (size_t)sA * 256 + lane;
    const float* pB = st_in + (size_t)sB * 256 + lane;
    const float ssA = pA[0], vxA = pA[64], vyA = pA[128], vzA = pA[192];
    const float ssB = pB[0], vxB = pB[64], vyB = pB[128], vzB = pB[192];
    DO_EDGE(A0, A1, A2, A3, A4, ssA, vxA, vyA, vzA);
    DO_EDGE(B0, B1, B2, B3, B4, ssB, vxB, vyB, vzB);
  }
  if (k < k1) {
    const int sA = esrc_s[k];
    const float4* gA = (const float4*)(egeo + (size_t)k * 20);
    const float4 A0 = gA[0], A1 = gA[1], A2 = gA[2], A3 = gA[3], A4 = gA[4];
    const float* pA = st_in + (size_t)sA * 256 + lane;
    const float ssA = pA[0], vxA = pA[64], vyA = pA[128], vzA = pA[192];
    DO_EDGE(A0, A1, A2, A3, A4, ssA, vxA, vyA, vzA);
  }
  const float inv_deg = 0.17677669529663687f;  // 1/sqrt(32)

  // node phase: sc_s / sc_v matvecs with per-type folded weights
  const int ty = nattr[node];
  const float* WsT = Ws + (size_t)ty * 8192;
  const float* WvT = Wv + (size_t)ty * 4096;
  const float* own = st_in + (size_t)node * 256 + lane;
  const float ys_own = own[0], v0x = own[64], v0y = own[128], v0z = own[192];
  float oS1 = 0.f, oS2 = 0.f, oV0 = 0.f, oV1 = 0.f, oV2 = 0.f;
  for (int s2 = 0; s2 < 64; ++s2) {
    const float yss = __shfl(ys_own, s2, 64);
    const float b0 = __shfl(v0x, s2, 64);
    const float b1 = __shfl(v0y, s2, 64);
    const float b2 = __shfl(v0z, s2, 64);
    const float wsA = WsT[s2 * 128 + lane];
    const float wsB = WsT[s2 * 128 + 64 + lane];
    const float wvv = WvT[s2 * 64 + lane];
    oS1 = fmaf(yss, wsA, oS1);
    oS2 = fmaf(yss, wsB, oS2);
    oV0 = fmaf(b0, wvv, oV0);
    oV1 = fmaf(b1, wvv, oV1);
    oV2 = fmaf(b2, wvv, oV2);
  }
  const float outS1 = oS1 + aS1 * inv_deg;
  const float outS2 = oS2 + aS2 * inv_deg;
  const float sig1 = 1.f / (1.f + expf(-outS1));
  const float gate = 1.f / (1.f + expf(-outS2));
  const float ysn = ys_own + HSTEP * outS1 * sig1;
  const float gf = HSTEP * gate;
  const float yvn0 = v0x + gf * (oV0 + aV0 * inv_deg);
  const float yvn1 = v0y + gf * (oV1 + aV1 * inv_deg);
  const float yvn2 = v0z + gf * (oV2 + aV2 * inv_deg);
  float* op = st_out + (size_t)node * 256 + lane;
  op[0] = ysn; op[64] = yvn0; op[128] = yvn1; op[192] = yvn2;

  // x_v[n,c,d] = sum_h yvn[h,d] * Q[h,c]  -> butterfly reduce 6 scalars
  const float q0 = Qm[lane * 2 + 0], q1 = Qm[lane * 2 + 1];
  float pr[6] = { yvn0 * q0, yvn1 * q0, yvn2 * q0,
                  yvn0 * q1, yvn1 * q1, yvn2 * q1 };
  #pragma unroll
  for (int mm = 1; mm < 64; mm <<= 1) {
    #pragma unroll
    for (int i = 0; i < 6; ++i) pr[i] += __shfl_xor(pr[i], mm, 64);
  }
  if (lane == 0) {
    #pragma unroll
    for (int i = 0; i < 6; ++i) xv_out[(size_t)node * 6 + i] = pr[i];
  }
}

// ---------------------------------------------------------------------------
extern "C" void kernel_launch(void* const* d_in, const int* in_sizes, int n_in,
                              void* d_out, int out_size, void* d_ws, size_t ws_size,
                              hipStream_t stream)
{
  const float* x     = (const float*)d_in[0];
  const int*   nattr = (const int*)d_in[2];
  const int*   esrc  = (const int*)d_in[3];
  const int*   edst  = (const int*)d_in[4];
  const float* embed = (const float*)d_in[5];
  const float* Ku    = (const float*)d_in[6];
  const float* Wss   = (const float*)d_in[7];
  const float* Wsv   = (const float*)d_in[8];
  const float* Wr1   = (const float*)d_in[9];
  const float* br1   = (const float*)d_in[10];
  const float* Wr2   = (const float*)d_in[11];
  const float* br2   = (const float*)d_in[12];
  const int n = in_sizes[0] / 6;
  const int m = in_sizes[3];

  char* p = (char*)d_ws;
  auto alloc = [&](size_t bytes) -> char* {
    char* r = p;
    p += (bytes + 255) & ~(size_t)255;
    return r;
  };
  int*   off    = (int*)alloc((size_t)(n + 1) * 4);
  int*   cursor = (int*)alloc((size_t)n * 4);
  int*   csr    = (int*)alloc((size_t)m * 4);
  int*   esrc_s = (int*)alloc((size_t)m * 4);
  int*   edst_s = (int*)alloc((size_t)m * 4);
  float* Q      = (float*)alloc(128 * 4);
  float* Ws     = (float*)alloc((size_t)LAYERS * NTYPES * 64 * 128 * 4);
  float* Wv     = (float*)alloc((size_t)LAYERS * NTYPES * 64 * 64 * 4);
  float* st0    = (float*)alloc((size_t)n * 256 * 4);
  float* st1    = (float*)alloc((size_t)n * 256 * 4);
  float* xvb    = (float*)alloc((size_t)n * 6 * 4);
  float* egeo   = (float*)alloc((size_t)m * 20 * 4);

  const int total_s = LAYERS * NTYPES * 64 * 128;
  const int total_v = LAYERS * NTYPES * 64 * 64;

  qr_kernel<<<1, 64, 0, stream>>>(Ku, Q);
  init_state<<<(n * 64 + 255) / 256, 256, 0, stream>>>(x, Q, st0, cursor, n);
  hist_kernel<<<(m + 255) / 256, 256, 0, stream>>>(edst, cursor, m);
  scan_kernel<<<1, 1024, 0, stream>>>(cursor, off, n);
  scatter_kernel<<<(m + 255) / 256, 256, 0, stream>>>(edst, cursor, csr, m);
  reorder_kernel<<<(m + 255) / 256, 256, 0, stream>>>(csr, esrc, edst, esrc_s, edst_s, m);
  type_weights<<<(total_s + total_v + 255) / 256, 256, 0, stream>>>(
      embed, Wss, Wsv, Ws, Wv, total_s, total_v);

  const float* xv_cur = x;
  const float* st_cur = st0;
  float* st_nxt = st1;
  for (int l = 0; l < LAYERS; ++l) {
    edge_geom<<<(m + 255) / 256, 256, 0, stream>>>(
        xv_cur, esrc_s, edst_s, Wr1 + l * NB * RH, br1 + l * RH, egeo, m);
    float* xv_out = (l == LAYERS - 1) ? (float*)d_out : xvb;
    gather_update<<<(n + 3) / 4, 256, 0, stream>>>(
        off, esrc_s, egeo, st_cur, nattr,
        Ws + (size_t)l * NTYPES * 8192, Wv + (size_t)l * NTYPES * 4096,
        Wr2 + l * RH * 256, br2 + l * 256, Q,
        st_nxt, xv_out, n);
    xv_cur = xv_out;
    float* ts = (float*)st_cur; st_cur = st_nxt; st_nxt = ts;
  }
}

// Round 4
// 343.529 us; speedup vs baseline: 3.2153x; 3.2153x over previous
//
#include <hip/hip_runtime.h>
#include <math.h>

#define NSC 64
#define NVC 64
#define EMB 32
#define NTYPES 20
#define NB 8
#define RH 16
#define LAYERS 2
#define CUTV 3.5f
#define HSTEP 0.1f

// ---------------------------------------------------------------------------
// Exact LAPACK-style Householder QR of Ku^T (64x2) -> Q (64x2), matching
// jnp/np.linalg.qr sign conventions (sgeqr2 + sorg2r).
// ---------------------------------------------------------------------------
__global__ void qr_kernel(const float* __restrict__ Ku, float* __restrict__ Q)
{
  if (threadIdx.x != 0 || blockIdx.x != 0) return;
  float A0[64], A1[64], v0[64], v1[64], t1[64];
  for (int i = 0; i < 64; ++i) { A0[i] = Ku[i]; A1[i] = Ku[64 + i]; }
  float alpha = A0[0];
  float xn2 = 0.f;
  for (int i = 1; i < 64; ++i) xn2 += A0[i] * A0[i];
  float beta0 = -copysignf(sqrtf(alpha * alpha + xn2), alpha);
  float tau0 = (beta0 - alpha) / beta0;
  float inv0 = 1.f / (alpha - beta0);
  v0[0] = 1.f;
  for (int i = 1; i < 64; ++i) v0[i] = A0[i] * inv0;
  float w = 0.f;
  for (int i = 0; i < 64; ++i) w += v0[i] * A1[i];
  for (int i = 0; i < 64; ++i) A1[i] -= tau0 * w * v0[i];
  float alpha1 = A1[1];
  float xn2b = 0.f;
  for (int i = 2; i < 64; ++i) xn2b += A1[i] * A1[i];
  float beta1 = -copysignf(sqrtf(alpha1 * alpha1 + xn2b), alpha1);
  float tau1 = (beta1 - alpha1) / beta1;
  float inv1 = 1.f / (alpha1 - beta1);
  v1[0] = 0.f; v1[1] = 1.f;
  for (int i = 2; i < 64; ++i) v1[i] = A1[i] * inv1;
  for (int i = 0; i < 64; ++i) t1[i] = ((i == 1) ? 1.f : 0.f) - tau1 * v1[i];
  float d = 0.f;
  for (int i = 0; i < 64; ++i) d += v0[i] * t1[i];
  for (int i = 0; i < 64; ++i) {
    float q0 = ((i == 0) ? 1.f : 0.f) - tau0 * v0[i];
    float q1 = t1[i] - tau0 * d * v0[i];
    Q[i * 2 + 0] = q0;
    Q[i * 2 + 1] = q1;
  }
}

// ---------------------------------------------------------------------------
// State layout: st[node][p][lane], p in {0:s, 1:vx, 2:vy, 3:vz}; 256 floats/node.
// ---------------------------------------------------------------------------
__global__ void init_state(const float* __restrict__ x, const float* __restrict__ Qm,
                           float* __restrict__ st0, int* __restrict__ cnt, int n)
{
  const int i = blockIdx.x * 256 + threadIdx.x;
  const int node = i >> 6, lane = i & 63;
  if (node < n) {
    const float q0 = Qm[lane * 2 + 0], q1 = Qm[lane * 2 + 1];
    const float* xp = x + (size_t)node * 6;
    float* sp = st0 + (size_t)node * 256 + lane;
    sp[0]   = 0.f;
    sp[64]  = xp[0] * q0 + xp[3] * q1;
    sp[128] = xp[1] * q0 + xp[4] * q1;
    sp[192] = xp[2] * q0 + xp[5] * q1;
  }
  if (i < n) cnt[i] = 0;
}

__global__ void hist_kernel(const int* __restrict__ edst, int* __restrict__ cnt, int m)
{
  const int e = blockIdx.x * 256 + threadIdx.x;
  if (e < m) atomicAdd(&cnt[edst[e]], 1);
}

// Single-block exclusive scan of counts.
__global__ void scan_kernel(int* cnt, int* off, int n)
{
  __shared__ int lds[1024];
  const int t = threadIdx.x;
  const int CH = (n + 1023) >> 10;
  const int base = t * CH;
  int local[16];
  int run = 0;
  for (int j = 0; j < CH; ++j) {
    int v = (base + j < n) ? cnt[base + j] : 0;
    local[j] = run;
    run += v;
  }
  lds[t] = run;
  __syncthreads();
  for (int s = 1; s < 1024; s <<= 1) {
    int v = (t >= s) ? lds[t - s] : 0;
    __syncthreads();
    lds[t] += v;
    __syncthreads();
  }
  const int excl = lds[t] - run;
  for (int j = 0; j < CH; ++j) {
    if (base + j < n) {
      int o = excl + local[j];
      off[base + j] = o;
      cnt[base + j] = o;
    }
  }
  if (t == 1023) off[n] = lds[1023];
}

__global__ void scatter_kernel(const int* __restrict__ edst, int* __restrict__ cursor,
                               int* __restrict__ csr, int m)
{
  const int e = blockIdx.x * 256 + threadIdx.x;
  if (e < m) {
    int p = atomicAdd(&cursor[edst[e]], 1);
    csr[p] = e;
  }
}

// Edge arrays in CSR (destination-sorted) order — computed once.
__global__ void reorder_kernel(const int* __restrict__ csr,
                               const int* __restrict__ esrc, const int* __restrict__ edst,
                               int* __restrict__ esrc_s, int* __restrict__ edst_s, int m)
{
  const int k = blockIdx.x * 256 + threadIdx.x;
  if (k < m) {
    const int e = csr[k];
    esrc_s[k] = esrc[e];
    edst_s[k] = edst[e];
  }
}

// ---------------------------------------------------------------------------
// Per-(layer,type) folded self-connection weights, output-parallel.
// ---------------------------------------------------------------------------
__global__ void type_weights(const float* __restrict__ embed,
                             const float* __restrict__ Wss,
                             const float* __restrict__ Wsv,
                             float* __restrict__ Ws, float* __restrict__ Wv,
                             int total_s, int total_v)
{
  const int i = blockIdx.x * 256 + threadIdx.x;
  if (i < total_s) {
    const int bid = i >> 13;
    const int p = i & 8191;
    const int l = bid / NTYPES, t = bid % NTYPES;
    const int s = p >> 7, o = p & 127;
    const float* ar = embed + t * EMB;
    const float* wp = Wss + ((size_t)(l * 64 + s) * EMB) * 128 + o;
    float acc = 0.f;
    #pragma unroll
    for (int e = 0; e < EMB; ++e) acc = fmaf(ar[e], wp[e * 128], acc);
    Ws[i] = acc;
  } else {
    const int j = i - total_s;
    if (j < total_v) {
      const int bid = j >> 12;
      const int p = j & 4095;
      const int l = bid / NTYPES, t = bid % NTYPES;
      const int v = p >> 6, u = p & 63;
      const float* ar = embed + t * EMB;
      const float* wp = Wsv + ((size_t)(l * 64 + v) * EMB) * 64 + u;
      float acc = 0.f;
      #pragma unroll
      for (int e = 0; e < EMB; ++e) acc = fmaf(ar[e], wp[e * 64], acc);
      Wv[j] = acc;
    }
  }
}

// ---------------------------------------------------------------------------
// Per-edge geometry + first MLP layer, in CSR order.
// egeo[k] = [eaX,eaY,eaZ,pad, hid0..15]
// ---------------------------------------------------------------------------
__global__ void edge_geom(const float* __restrict__ xv,
                          const int* __restrict__ esrc_s, const int* __restrict__ edst_s,
                          const float* __restrict__ Wr1l, const float* __restrict__ br1l,
                          float* __restrict__ egeo, int m)
{
  const int k = blockIdx.x * 256 + threadIdx.x;
  if (k >= m) return;
  const int s = esrc_s[k], d = edst_s[k];
  const float ex = xv[(size_t)s * 6 + 0] - xv[(size_t)d * 6 + 0];
  const float ey = xv[(size_t)s * 6 + 1] - xv[(size_t)d * 6 + 1];
  const float ez = xv[(size_t)s * 6 + 2] - xv[(size_t)d * 6 + 2];
  const float len = sqrtf(ex * ex + ey * ey + ez * ez);
  const float invl = 1.f / len;
  const float u = len * (1.f / CUTV);
  const float vv = 2.f * (u - 1.f);
  float cut = 0.5f * (1.f - cosf((float)M_PI * vv));
  cut = (vv > 0.f) ? 0.f : cut;
  cut = (vv < -1.f) ? 1.f : cut;
  const float cc = cut * 1.7320508075688772f * invl;
  float4* outp = (float4*)(egeo + (size_t)k * 20);
  outp[0] = make_float4(cc * ex, cc * ey, cc * ez, 0.f);
  float bess[NB];
  const float amp = 2.1380899352993948f * invl;  // sqrt(2/CUT)*sqrt(NB)
  const float arg = (float)M_PI * len * (1.f / CUTV);
  #pragma unroll
  for (int kk = 0; kk < NB; ++kk) bess[kk] = amp * sinf(arg * (float)(kk + 1));
  float hid[RH];
  #pragma unroll
  for (int j = 0; j < RH; ++j) {
    float h = br1l[j];
    #pragma unroll
    for (int kk = 0; kk < NB; ++kk) h = fmaf(bess[kk], Wr1l[kk * RH + j], h);
    hid[j] = h / (1.f + expf(-h));   // silu
  }
  outp[1] = make_float4(hid[0], hid[1], hid[2], hid[3]);
  outp[2] = make_float4(hid[4], hid[5], hid[6], hid[7]);
  outp[3] = make_float4(hid[8], hid[9], hid[10], hid[11]);
  outp[4] = make_float4(hid[12], hid[13], hid[14], hid[15]);
}

// ---------------------------------------------------------------------------
// One wave per destination node; CSR-sequential edge streams; 1-deep prefetch
// of next edge's (src, geometry) so the esrc->st dependent chain spans
// iterations. MLP written as explicit FMAs on float4 components (no local
// arrays -> nothing for the allocator to demote to scratch).
// ---------------------------------------------------------------------------
#define MLP_STEP(h, idx)                                                     \
  wA = fmaf((h), wr2A[idx], wA);                                             \
  wB = fmaf((h), wr2B[idx], wB);                                             \
  wC = fmaf((h), wr2C[idx], wC);                                             \
  wD = fmaf((h), wr2D[idx], wD);

__global__ __launch_bounds__(256, 2) void gather_update(
    const int* __restrict__ off, const int* __restrict__ esrc_s,
    const float* __restrict__ egeo,
    const float* __restrict__ st_in, const int* __restrict__ nattr,
    const float* __restrict__ Ws, const float* __restrict__ Wv,
    const float* __restrict__ Wr2l, const float* __restrict__ br2l,
    const float* __restrict__ Qm,
    float* __restrict__ st_out, float* __restrict__ xv_out, int n)
{
  const int lane = threadIdx.x & 63;
  const int node = blockIdx.x * 4 + (threadIdx.x >> 6);
  if (node >= n) return;

  float wr2A[RH], wr2B[RH], wr2C[RH], wr2D[RH];
  #pragma unroll
  for (int j = 0; j < RH; ++j) {
    const float* r = Wr2l + j * 256 + lane;
    wr2A[j] = r[0]; wr2B[j] = r[64]; wr2C[j] = r[128]; wr2D[j] = r[192];
  }
  const float bA = br2l[lane], bB = br2l[64 + lane],
              bC = br2l[128 + lane], bD = br2l[192 + lane];

  float aS1 = 0.f, aS2 = 0.f, aV0 = 0.f, aV1 = 0.f, aV2 = 0.f;
  const int k0 = off[node], k1 = off[node + 1];
  if (k0 < k1) {
    // prefetch edge k0
    int srcN = esrc_s[k0];
    const float4* gN = (const float4*)(egeo + (size_t)k0 * 20);
    float4 N0 = gN[0], N1 = gN[1], N2 = gN[2], N3 = gN[3], N4 = gN[4];
    for (int k = k0; k < k1; ++k) {
      const int srcC = srcN;
      const float4 C0 = N0, C1 = N1, C2 = N2, C3 = N3, C4 = N4;
      // issue next edge's loads before current compute
      const int kn = (k + 1 < k1) ? (k + 1) : k;
      srcN = esrc_s[kn];
      const float4* gp = (const float4*)(egeo + (size_t)kn * 20);
      N0 = gp[0]; N1 = gp[1]; N2 = gp[2]; N3 = gp[3]; N4 = gp[4];
      // current edge's state gather (src known since previous iteration)
      const float* pC = st_in + (size_t)srcC * 256 + lane;
      const float ss = pC[0], vx = pC[64], vy = pC[128], vz = pC[192];
      // radial MLP second layer: 64 FMAs on held coefficients
      float wA = bA, wB = bB, wC = bC, wD = bD;
      MLP_STEP(C1.x, 0)  MLP_STEP(C1.y, 1)  MLP_STEP(C1.z, 2)  MLP_STEP(C1.w, 3)
      MLP_STEP(C2.x, 4)  MLP_STEP(C2.y, 5)  MLP_STEP(C2.z, 6)  MLP_STEP(C2.w, 7)
      MLP_STEP(C3.x, 8)  MLP_STEP(C3.y, 9)  MLP_STEP(C3.z, 10) MLP_STEP(C3.w, 11)
      MLP_STEP(C4.x, 12) MLP_STEP(C4.y, 13) MLP_STEP(C4.z, 14) MLP_STEP(C4.w, 15)
      const float dt = vx * C0.x + vy * C0.y + vz * C0.z;
      aS1 = fmaf(wB, dt, aS1);
      aS2 = fmaf(wD, dt, aS2);
      const float t = wA * ss;
      aV0 += t * C0.x + wC * (vy * C0.z - vz * C0.y);
      aV1 += t * C0.y + wC * (vz * C0.x - vx * C0.z);
      aV2 += t * C0.z + wC * (vx * C0.y - vy * C0.x);
    }
  }
  const float inv_deg = 0.17677669529663687f;  // 1/sqrt(32)

  // node phase: sc_s / sc_v matvecs with per-type folded weights
  const int ty = nattr[node];
  const float* WsT = Ws + (size_t)ty * 8192;
  const float* WvT = Wv + (size_t)ty * 4096;
  const float* own = st_in + (size_t)node * 256 + lane;
  const float ys_own = own[0], v0x = own[64], v0y = own[128], v0z = own[192];
  float oS1 = 0.f, oS2 = 0.f, oV0 = 0.f, oV1 = 0.f, oV2 = 0.f;
  #pragma unroll 4
  for (int s2 = 0; s2 < 64; ++s2) {
    const float yss = __shfl(ys_own, s2, 64);
    const float b0 = __shfl(v0x, s2, 64);
    const float b1 = __shfl(v0y, s2, 64);
    const float b2 = __shfl(v0z, s2, 64);
    const float wsA = WsT[s2 * 128 + lane];
    const float wsB = WsT[s2 * 128 + 64 + lane];
    const float wvv = WvT[s2 * 64 + lane];
    oS1 = fmaf(yss, wsA, oS1);
    oS2 = fmaf(yss, wsB, oS2);
    oV0 = fmaf(b0, wvv, oV0);
    oV1 = fmaf(b1, wvv, oV1);
    oV2 = fmaf(b2, wvv, oV2);
  }
  const float outS1 = oS1 + aS1 * inv_deg;
  const float outS2 = oS2 + aS2 * inv_deg;
  const float sig1 = 1.f / (1.f + expf(-outS1));
  const float gate = 1.f / (1.f + expf(-outS2));
  const float ysn = ys_own + HSTEP * outS1 * sig1;
  const float gf = HSTEP * gate;
  const float yvn0 = v0x + gf * (oV0 + aV0 * inv_deg);
  const float yvn1 = v0y + gf * (oV1 + aV1 * inv_deg);
  const float yvn2 = v0z + gf * (oV2 + aV2 * inv_deg);
  float* op = st_out + (size_t)node * 256 + lane;
  op[0] = ysn; op[64] = yvn0; op[128] = yvn1; op[192] = yvn2;

  // x_v[n,c,d] = sum_h yvn[h,d] * Q[h,c]  -> butterfly reduce 6 scalars
  const float q0 = Qm[lane * 2 + 0], q1 = Qm[lane * 2 + 1];
  float pr[6] = { yvn0 * q0, yvn1 * q0, yvn2 * q0,
                  yvn0 * q1, yvn1 * q1, yvn2 * q1 };
  #pragma unroll
  for (int mm = 1; mm < 64; mm <<= 1) {
    #pragma unroll
    for (int i = 0; i < 6; ++i) pr[i] += __shfl_xor(pr[i], mm, 64);
  }
  if (lane == 0) {
    #pragma unroll
    for (int i = 0; i < 6; ++i) xv_out[(size_t)node * 6 + i] = pr[i];
  }
}

// ---------------------------------------------------------------------------
extern "C" void kernel_launch(void* const* d_in, const int* in_sizes, int n_in,
                              void* d_out, int out_size, void* d_ws, size_t ws_size,
                              hipStream_t stream)
{
  const float* x     = (const float*)d_in[0];
  const int*   nattr = (const int*)d_in[2];
  const int*   esrc  = (const int*)d_in[3];
  const int*   edst  = (const int*)d_in[4];
  const float* embed = (const float*)d_in[5];
  const float* Ku    = (const float*)d_in[6];
  const float* Wss   = (const float*)d_in[7];
  const float* Wsv   = (const float*)d_in[8];
  const float* Wr1   = (const float*)d_in[9];
  const float* br1   = (const float*)d_in[10];
  const float* Wr2   = (const float*)d_in[11];
  const float* br2   = (const float*)d_in[12];
  const int n = in_sizes[0] / 6;
  const int m = in_sizes[3];

  char* p = (char*)d_ws;
  auto alloc = [&](size_t bytes) -> char* {
    char* r = p;
    p += (bytes + 255) & ~(size_t)255;
    return r;
  };
  int*   off    = (int*)alloc((size_t)(n + 1) * 4);
  int*   cursor = (int*)alloc((size_t)n * 4);
  int*   csr    = (int*)alloc((size_t)m * 4);
  int*   esrc_s = (int*)alloc((size_t)m * 4);
  int*   edst_s = (int*)alloc((size_t)m * 4);
  float* Q      = (float*)alloc(128 * 4);
  float* Ws     = (float*)alloc((size_t)LAYERS * NTYPES * 64 * 128 * 4);
  float* Wv     = (float*)alloc((size_t)LAYERS * NTYPES * 64 * 64 * 4);
  float* st0    = (float*)alloc((size_t)n * 256 * 4);
  float* st1    = (float*)alloc((size_t)n * 256 * 4);
  float* xvb    = (float*)alloc((size_t)n * 6 * 4);
  float* egeo   = (float*)alloc((size_t)m * 20 * 4);

  const int total_s = LAYERS * NTYPES * 64 * 128;
  const int total_v = LAYERS * NTYPES * 64 * 64;

  qr_kernel<<<1, 64, 0, stream>>>(Ku, Q);
  init_state<<<(n * 64 + 255) / 256, 256, 0, stream>>>(x, Q, st0, cursor, n);
  hist_kernel<<<(m + 255) / 256, 256, 0, stream>>>(edst, cursor, m);
  scan_kernel<<<1, 1024, 0, stream>>>(cursor, off, n);
  scatter_kernel<<<(m + 255) / 256, 256, 0, stream>>>(edst, cursor, csr, m);
  reorder_kernel<<<(m + 255) / 256, 256, 0, stream>>>(csr, esrc, edst, esrc_s, edst_s, m);
  type_weights<<<(total_s + total_v + 255) / 256, 256, 0, stream>>>(
      embed, Wss, Wsv, Ws, Wv, total_s, total_v);

  const float* xv_cur = x;
  const float* st_cur = st0;
  float* st_nxt = st1;
  for (int l = 0; l < LAYERS; ++l) {
    edge_geom<<<(m + 255) / 256, 256, 0, stream>>>(
        xv_cur, esrc_s, edst_s, Wr1 + l * NB * RH, br1 + l * RH, egeo, m);
    float* xv_out = (l == LAYERS - 1) ? (float*)d_out : xvb;
    gather_update<<<(n + 3) / 4, 256, 0, stream>>>(
        off, esrc_s, egeo, st_cur, nattr,
        Ws + (size_t)l * NTYPES * 8192, Wv + (size_t)l * NTYPES * 4096,
        Wr2 + l * RH * 256, br2 + l * 256, Q,
        st_nxt, xv_out, n);
    xv_cur = xv_out;
    float* ts = (float*)st_cur; st_cur = st_nxt; st_nxt = ts;
  }
}

// Round 5
// 317.907 us; speedup vs baseline: 3.4744x; 1.0806x over previous
//
#include <hip/hip_runtime.h>
#include <math.h>

#define NSC 64
#define NVC 64
#define EMB 32
#define NTYPES 20
#define NB 8
#define RH 16
#define LAYERS 2
#define CUTV 3.5f
#define HSTEP 0.1f

// ---------------------------------------------------------------------------
// Exact LAPACK-style Householder QR of Ku^T (64x2) -> Q (64x2), wave-parallel.
// ---------------------------------------------------------------------------
__device__ __forceinline__ float wave_sum(float t)
{
  #pragma unroll
  for (int mm = 1; mm < 64; mm <<= 1) t += __shfl_xor(t, mm, 64);
  return t;
}

__global__ void qr_kernel(const float* __restrict__ Ku, float* __restrict__ Q)
{
  const int i = threadIdx.x;  // 64 lanes
  float a0 = Ku[i], a1 = Ku[64 + i];
  const float xn2 = wave_sum((i >= 1) ? a0 * a0 : 0.f);
  const float alpha = __shfl(a0, 0, 64);
  const float beta0 = -copysignf(sqrtf(alpha * alpha + xn2), alpha);
  const float tau0 = (beta0 - alpha) / beta0;
  const float inv0 = 1.f / (alpha - beta0);
  const float v0 = (i == 0) ? 1.f : a0 * inv0;
  const float w = wave_sum(v0 * a1);
  a1 -= tau0 * w * v0;
  const float alpha1 = __shfl(a1, 1, 64);
  const float xn2b = wave_sum((i >= 2) ? a1 * a1 : 0.f);
  const float beta1 = -copysignf(sqrtf(alpha1 * alpha1 + xn2b), alpha1);
  const float tau1 = (beta1 - alpha1) / beta1;
  const float inv1 = 1.f / (alpha1 - beta1);
  const float v1 = (i == 0) ? 0.f : ((i == 1) ? 1.f : a1 * inv1);
  const float t1v = ((i == 1) ? 1.f : 0.f) - tau1 * v1;
  const float d = wave_sum(v0 * t1v);
  Q[i * 2 + 0] = ((i == 0) ? 1.f : 0.f) - tau0 * v0;
  Q[i * 2 + 1] = t1v - tau0 * d * v0;
}

// ---------------------------------------------------------------------------
// State layout: st[node][p][lane], p in {0:s, 1:vx, 2:vy, 3:vz}; 256 floats/node.
// ---------------------------------------------------------------------------
__global__ void init_state(const float* __restrict__ x, const float* __restrict__ Qm,
                           float* __restrict__ st0, int* __restrict__ cnt, int n)
{
  const int i = blockIdx.x * 256 + threadIdx.x;
  const int node = i >> 6, lane = i & 63;
  if (node < n) {
    const float q0 = Qm[lane * 2 + 0], q1 = Qm[lane * 2 + 1];
    const float* xp = x + (size_t)node * 6;
    float* sp = st0 + (size_t)node * 256 + lane;
    sp[0]   = 0.f;
    sp[64]  = xp[0] * q0 + xp[3] * q1;
    sp[128] = xp[1] * q0 + xp[4] * q1;
    sp[192] = xp[2] * q0 + xp[5] * q1;
  }
  if (i < n) cnt[i] = 0;
}

__global__ void hist_kernel(const int* __restrict__ edst, int* __restrict__ cnt, int m)
{
  const int e = blockIdx.x * 256 + threadIdx.x;
  if (e < m) atomicAdd(&cnt[edst[e]], 1);
}

// Single-block exclusive scan of counts.
__global__ void scan_kernel(int* cnt, int* off, int n)
{
  __shared__ int lds[1024];
  const int t = threadIdx.x;
  const int CH = (n + 1023) >> 10;
  const int base = t * CH;
  int local[16];
  int run = 0;
  for (int j = 0; j < CH; ++j) {
    int v = (base + j < n) ? cnt[base + j] : 0;
    local[j] = run;
    run += v;
  }
  lds[t] = run;
  __syncthreads();
  for (int s = 1; s < 1024; s <<= 1) {
    int v = (t >= s) ? lds[t - s] : 0;
    __syncthreads();
    lds[t] += v;
    __syncthreads();
  }
  const int excl = lds[t] - run;
  for (int j = 0; j < CH; ++j) {
    if (base + j < n) {
      int o = excl + local[j];
      off[base + j] = o;
      cnt[base + j] = o;
    }
  }
  if (t == 1023) off[n] = lds[1023];
}

__global__ void scatter_kernel(const int* __restrict__ edst, int* __restrict__ cursor,
                               int* __restrict__ csr, int m)
{
  const int e = blockIdx.x * 256 + threadIdx.x;
  if (e < m) {
    int p = atomicAdd(&cursor[edst[e]], 1);
    csr[p] = e;
  }
}

// Edge arrays in CSR (destination-sorted) order — computed once.
__global__ void reorder_kernel(const int* __restrict__ csr,
                               const int* __restrict__ esrc, const int* __restrict__ edst,
                               int* __restrict__ esrc_s, int* __restrict__ edst_s, int m)
{
  const int k = blockIdx.x * 256 + threadIdx.x;
  if (k < m) {
    const int e = csr[k];
    esrc_s[k] = esrc[e];
    edst_s[k] = edst[e];
  }
}

// ---------------------------------------------------------------------------
// Per-(layer,type) folded self-connection weights, output-parallel.
// ---------------------------------------------------------------------------
__global__ void type_weights(const float* __restrict__ embed,
                             const float* __restrict__ Wss,
                             const float* __restrict__ Wsv,
                             float* __restrict__ Ws, float* __restrict__ Wv,
                             int total_s, int total_v)
{
  const int i = blockIdx.x * 256 + threadIdx.x;
  if (i < total_s) {
    const int bid = i >> 13;
    const int p = i & 8191;
    const int l = bid / NTYPES, t = bid % NTYPES;
    const int s = p >> 7, o = p & 127;
    const float* ar = embed + t * EMB;
    const float* wp = Wss + ((size_t)(l * 64 + s) * EMB) * 128 + o;
    float acc = 0.f;
    #pragma unroll
    for (int e = 0; e < EMB; ++e) acc = fmaf(ar[e], wp[e * 128], acc);
    Ws[i] = acc;
  } else {
    const int j = i - total_s;
    if (j < total_v) {
      const int bid = j >> 12;
      const int p = j & 4095;
      const int l = bid / NTYPES, t = bid % NTYPES;
      const int v = p >> 6, u = p & 63;
      const float* ar = embed + t * EMB;
      const float* wp = Wsv + ((size_t)(l * 64 + v) * EMB) * 64 + u;
      float acc = 0.f;
      #pragma unroll
      for (int e = 0; e < EMB; ++e) acc = fmaf(ar[e], wp[e * 64], acc);
      Wv[j] = acc;
    }
  }
}

// ---------------------------------------------------------------------------
// Per-edge geometry + first MLP layer, in CSR order.
// egeo[k] = [eaX,eaY,eaZ,pad, hid0..15]
// One __sincosf; bessel sines via Chebyshev recurrence; cutoff cos from c.
// ---------------------------------------------------------------------------
__global__ void edge_geom(const float* __restrict__ xv,
                          const int* __restrict__ esrc_s, const int* __restrict__ edst_s,
                          const float* __restrict__ Wr1l, const float* __restrict__ br1l,
                          float* __restrict__ egeo, int m)
{
  const int k = blockIdx.x * 256 + threadIdx.x;
  if (k >= m) return;
  const int s = esrc_s[k], d = edst_s[k];
  const float ex = xv[(size_t)s * 6 + 0] - xv[(size_t)d * 6 + 0];
  const float ey = xv[(size_t)s * 6 + 1] - xv[(size_t)d * 6 + 1];
  const float ez = xv[(size_t)s * 6 + 2] - xv[(size_t)d * 6 + 2];
  const float len = sqrtf(ex * ex + ey * ey + ez * ez);
  const float invl = 1.f / len;
  const float u = len * (1.f / CUTV);
  const float arg = (float)M_PI * u;      // a
  float sa, ca;
  __sincosf(arg, &sa, &ca);
  // smooth cutoff: cos(pi*v) with v = 2(u-1) -> cos(2*pi*u) = 2c^2 - 1
  const float vv = 2.f * (u - 1.f);
  float cut = 0.5f * (1.f - (2.f * ca * ca - 1.f));
  cut = (vv > 0.f) ? 0.f : cut;
  cut = (vv < -1.f) ? 1.f : cut;
  const float cc = cut * 1.7320508075688772f * invl;
  float4* outp = (float4*)(egeo + (size_t)k * 20);
  outp[0] = make_float4(cc * ex, cc * ey, cc * ez, 0.f);
  // bess[j] = amp * sin((j+1)*a) via s_{j+1} = 2c*s_j - s_{j-1}
  float bess[NB];
  const float amp = 2.1380899352993948f * invl;  // sqrt(2/CUT)*sqrt(NB)
  const float twoc = 2.f * ca;
  float sm1 = 0.f, scur = sa;
  #pragma unroll
  for (int kk = 0; kk < NB; ++kk) {
    bess[kk] = amp * scur;
    const float snext = twoc * scur - sm1;
    sm1 = scur; scur = snext;
  }
  float hid[RH];
  #pragma unroll
  for (int j = 0; j < RH; ++j) {
    float h = br1l[j];
    #pragma unroll
    for (int kk = 0; kk < NB; ++kk) h = fmaf(bess[kk], Wr1l[kk * RH + j], h);
    hid[j] = h / (1.f + expf(-h));   // silu
  }
  outp[1] = make_float4(hid[0], hid[1], hid[2], hid[3]);
  outp[2] = make_float4(hid[4], hid[5], hid[6], hid[7]);
  outp[3] = make_float4(hid[8], hid[9], hid[10], hid[11]);
  outp[4] = make_float4(hid[12], hid[13], hid[14], hid[15]);
}

// ---------------------------------------------------------------------------
// One wave per destination node; CSR-sequential edge streams.
// wr2 coefficients pinned in VGPRs via opaque asm (compiler cannot
// rematerialize -> no per-iteration reloads). st gather prefetched one edge
// ahead (src index two ahead); geometry prefetched one edge ahead.
// ---------------------------------------------------------------------------
#define MLP_STEP(h, idx)                                                     \
  wA = fmaf((h), wr2A[idx], wA);                                             \
  wB = fmaf((h), wr2B[idx], wB);                                             \
  wC = fmaf((h), wr2C[idx], wC);                                             \
  wD = fmaf((h), wr2D[idx], wD);

__global__ __launch_bounds__(256, 3) void gather_update(
    const int* __restrict__ off, const int* __restrict__ esrc_s,
    const float* __restrict__ egeo,
    const float* __restrict__ st_in, const int* __restrict__ nattr,
    const float* __restrict__ Ws, const float* __restrict__ Wv,
    const float* __restrict__ Wr2l, const float* __restrict__ br2l,
    const float* __restrict__ Qm,
    float* __restrict__ st_out, float* __restrict__ xv_out, int n)
{
  const int lane = threadIdx.x & 63;
  const int node = blockIdx.x * 4 + (threadIdx.x >> 6);
  if (node >= n) return;

  float wr2A[RH], wr2B[RH], wr2C[RH], wr2D[RH];
  #pragma unroll
  for (int j = 0; j < RH; ++j) {
    const float* r = Wr2l + j * 256 + lane;
    wr2A[j] = r[0]; wr2B[j] = r[64]; wr2C[j] = r[128]; wr2D[j] = r[192];
  }
  // Pin the 64 coefficients in VGPRs: asm output is opaque, so the compiler
  // must keep these live instead of re-loading from memory in the edge loop.
  #pragma unroll
  for (int j = 0; j < RH; ++j) {
    asm volatile("" : "+v"(wr2A[j]), "+v"(wr2B[j]), "+v"(wr2C[j]), "+v"(wr2D[j]));
  }
  const float bA = br2l[lane], bB = br2l[64 + lane],
              bC = br2l[128 + lane], bD = br2l[192 + lane];

  float aS1 = 0.f, aS2 = 0.f, aV0 = 0.f, aV1 = 0.f, aV2 = 0.f;
  const int k0 = off[node], k1 = off[node + 1];
  if (k0 < k1) {
    // software pipeline: st + geo for edge k prefetched at iteration k-1
    const int src0 = esrc_s[k0];
    const float* p0 = st_in + (size_t)src0 * 256 + lane;
    float ssN = p0[0], vxN = p0[64], vyN = p0[128], vzN = p0[192];
    const float4* g0 = (const float4*)(egeo + (size_t)k0 * 20);
    float4 N0 = g0[0], N1 = g0[1], N2 = g0[2], N3 = g0[3], N4 = g0[4];
    int srcN = (k0 + 1 < k1) ? esrc_s[k0 + 1] : src0;
    for (int k = k0; k < k1; ++k) {
      // consume prefetched current values
      const float ss = ssN, vx = vxN, vy = vyN, vz = vzN;
      const float4 C0 = N0, C1 = N1, C2 = N2, C3 = N3, C4 = N4;
      // issue next edge's st loads (src known since last iteration)
      const float* pN = st_in + (size_t)srcN * 256 + lane;
      ssN = pN[0]; vxN = pN[64]; vyN = pN[128]; vzN = pN[192];
      // issue next edge's geometry loads
      const int kn = (k + 1 < k1) ? (k + 1) : k;
      const float4* gp = (const float4*)(egeo + (size_t)kn * 20);
      N0 = gp[0]; N1 = gp[1]; N2 = gp[2]; N3 = gp[3]; N4 = gp[4];
      // src index two ahead
      srcN = (k + 2 < k1) ? esrc_s[k + 2] : srcN;
      // radial MLP second layer: 64 FMAs on pinned coefficients
      float wA = bA, wB = bB, wC = bC, wD = bD;
      MLP_STEP(C1.x, 0)  MLP_STEP(C1.y, 1)  MLP_STEP(C1.z, 2)  MLP_STEP(C1.w, 3)
      MLP_STEP(C2.x, 4)  MLP_STEP(C2.y, 5)  MLP_STEP(C2.z, 6)  MLP_STEP(C2.w, 7)
      MLP_STEP(C3.x, 8)  MLP_STEP(C3.y, 9)  MLP_STEP(C3.z, 10) MLP_STEP(C3.w, 11)
      MLP_STEP(C4.x, 12) MLP_STEP(C4.y, 13) MLP_STEP(C4.z, 14) MLP_STEP(C4.w, 15)
      const float dt = vx * C0.x + vy * C0.y + vz * C0.z;
      aS1 = fmaf(wB, dt, aS1);
      aS2 = fmaf(wD, dt, aS2);
      const float t = wA * ss;
      aV0 += t * C0.x + wC * (vy * C0.z - vz * C0.y);
      aV1 += t * C0.y + wC * (vz * C0.x - vx * C0.z);
      aV2 += t * C0.z + wC * (vx * C0.y - vy * C0.x);
    }
  }
  const float inv_deg = 0.17677669529663687f;  // 1/sqrt(32)

  // node phase: sc_s / sc_v matvecs with per-type folded weights
  const int ty = nattr[node];
  const float* WsT = Ws + (size_t)ty * 8192;
  const float* WvT = Wv + (size_t)ty * 4096;
  const float* own = st_in + (size_t)node * 256 + lane;
  const float ys_own = own[0], v0x = own[64], v0y = own[128], v0z = own[192];
  float oS1 = 0.f, oS2 = 0.f, oV0 = 0.f, oV1 = 0.f, oV2 = 0.f;
  #pragma unroll 4
  for (int s2 = 0; s2 < 64; ++s2) {
    const float yss = __shfl(ys_own, s2, 64);
    const float b0 = __shfl(v0x, s2, 64);
    const float b1 = __shfl(v0y, s2, 64);
    const float b2 = __shfl(v0z, s2, 64);
    const float wsA = WsT[s2 * 128 + lane];
    const float wsB = WsT[s2 * 128 + 64 + lane];
    const float wvv = WvT[s2 * 64 + lane];
    oS1 = fmaf(yss, wsA, oS1);
    oS2 = fmaf(yss, wsB, oS2);
    oV0 = fmaf(b0, wvv, oV0);
    oV1 = fmaf(b1, wvv, oV1);
    oV2 = fmaf(b2, wvv, oV2);
  }
  const float outS1 = oS1 + aS1 * inv_deg;
  const float outS2 = oS2 + aS2 * inv_deg;
  const float sig1 = 1.f / (1.f + expf(-outS1));
  const float gate = 1.f / (1.f + expf(-outS2));
  const float ysn = ys_own + HSTEP * outS1 * sig1;
  const float gf = HSTEP * gate;
  const float yvn0 = v0x + gf * (oV0 + aV0 * inv_deg);
  const float yvn1 = v0y + gf * (oV1 + aV1 * inv_deg);
  const float yvn2 = v0z + gf * (oV2 + aV2 * inv_deg);
  float* op = st_out + (size_t)node * 256 + lane;
  op[0] = ysn; op[64] = yvn0; op[128] = yvn1; op[192] = yvn2;

  // x_v[n,c,d] = sum_h yvn[h,d] * Q[h,c]  -> butterfly reduce 6 scalars
  const float q0 = Qm[lane * 2 + 0], q1 = Qm[lane * 2 + 1];
  float pr[6] = { yvn0 * q0, yvn1 * q0, yvn2 * q0,
                  yvn0 * q1, yvn1 * q1, yvn2 * q1 };
  #pragma unroll
  for (int mm = 1; mm < 64; mm <<= 1) {
    #pragma unroll
    for (int i = 0; i < 6; ++i) pr[i] += __shfl_xor(pr[i], mm, 64);
  }
  if (lane == 0) {
    #pragma unroll
    for (int i = 0; i < 6; ++i) xv_out[(size_t)node * 6 + i] = pr[i];
  }
}

// ---------------------------------------------------------------------------
extern "C" void kernel_launch(void* const* d_in, const int* in_sizes, int n_in,
                              void* d_out, int out_size, void* d_ws, size_t ws_size,
                              hipStream_t stream)
{
  const float* x     = (const float*)d_in[0];
  const int*   nattr = (const int*)d_in[2];
  const int*   esrc  = (const int*)d_in[3];
  const int*   edst  = (const int*)d_in[4];
  const float* embed = (const float*)d_in[5];
  const float* Ku    = (const float*)d_in[6];
  const float* Wss   = (const float*)d_in[7];
  const float* Wsv   = (const float*)d_in[8];
  const float* Wr1   = (const float*)d_in[9];
  const float* br1   = (const float*)d_in[10];
  const float* Wr2   = (const float*)d_in[11];
  const float* br2   = (const float*)d_in[12];
  const int n = in_sizes[0] / 6;
  const int m = in_sizes[3];

  char* p = (char*)d_ws;
  auto alloc = [&](size_t bytes) -> char* {
    char* r = p;
    p += (bytes + 255) & ~(size_t)255;
    return r;
  };
  int*   off    = (int*)alloc((size_t)(n + 1) * 4);
  int*   cursor = (int*)alloc((size_t)n * 4);
  int*   csr    = (int*)alloc((size_t)m * 4);
  int*   esrc_s = (int*)alloc((size_t)m * 4);
  int*   edst_s = (int*)alloc((size_t)m * 4);
  float* Q      = (float*)alloc(128 * 4);
  float* Ws     = (float*)alloc((size_t)LAYERS * NTYPES * 64 * 128 * 4);
  float* Wv     = (float*)alloc((size_t)LAYERS * NTYPES * 64 * 64 * 4);
  float* st0    = (float*)alloc((size_t)n * 256 * 4);
  float* st1    = (float*)alloc((size_t)n * 256 * 4);
  float* xvb    = (float*)alloc((size_t)n * 6 * 4);
  float* egeo   = (float*)alloc((size_t)m * 20 * 4);

  const int total_s = LAYERS * NTYPES * 64 * 128;
  const int total_v = LAYERS * NTYPES * 64 * 64;

  qr_kernel<<<1, 64, 0, stream>>>(Ku, Q);
  init_state<<<(n * 64 + 255) / 256, 256, 0, stream>>>(x, Q, st0, cursor, n);
  hist_kernel<<<(m + 255) / 256, 256, 0, stream>>>(edst, cursor, m);
  scan_kernel<<<1, 1024, 0, stream>>>(cursor, off, n);
  scatter_kernel<<<(m + 255) / 256, 256, 0, stream>>>(edst, cursor, csr, m);
  reorder_kernel<<<(m + 255) / 256, 256, 0, stream>>>(csr, esrc, edst, esrc_s, edst_s, m);
  type_weights<<<(total_s + total_v + 255) / 256, 256, 0, stream>>>(
      embed, Wss, Wsv, Ws, Wv, total_s, total_v);

  const float* xv_cur = x;
  const float* st_cur = st0;
  float* st_nxt = st1;
  for (int l = 0; l < LAYERS; ++l) {
    edge_geom<<<(m + 255) / 256, 256, 0, stream>>>(
        xv_cur, esrc_s, edst_s, Wr1 + l * NB * RH, br1 + l * RH, egeo, m);
    float* xv_out = (l == LAYERS - 1) ? (float*)d_out : xvb;
    gather_update<<<(n + 3) / 4, 256, 0, stream>>>(
        off, esrc_s, egeo, st_cur, nattr,
        Ws + (size_t)l * NTYPES * 8192, Wv + (size_t)l * NTYPES * 4096,
        Wr2 + l * RH * 256, br2 + l * 256, Q,
        st_nxt, xv_out, n);
    xv_cur = xv_out;
    float* ts = (float*)st_cur; st_cur = st_nxt; st_nxt = ts;
  }
}